// Round 17
// baseline (363.362 us; speedup 1.0000x reference)
//
#include <hip/hip_runtime.h>
#include <hip/hip_fp16.h>
#include <math.h>

#define N1 10242
#define N2 40962
#define N3 163842

constexpr float SLOPE = 0.2f;
constexpr int TB = 256;

static inline int cdiv(int a, int b) { return (a + b - 1) / b; }

typedef unsigned int u32;

__device__ inline u32 packh2(float a, float b) {
    __half2 h = __floats2half2_rn(a, b);
    return *reinterpret_cast<u32*>(&h);
}
__device__ inline float2 unpackh2(u32 v) {
    __half2 h;
    *reinterpret_cast<u32*>(&h) = v;
    return __half22float2(h);
}

// ---- block reduce of K fp32 per thread via padded LDS transpose (conflict-free) ----
template <int K>
__device__ void block_reduce_part(const float* v, float* __restrict__ part_out, int bid) {
    constexpr int S = K + 1;
    constexpr int CH = 16;
    constexpr int RW = TB / CH;
    __shared__ float sh[TB * S];
    __shared__ float tmp[CH * K];
    int tid = threadIdx.x;
#pragma unroll
    for (int k = 0; k < K; ++k) sh[tid * S + k] = v[k];
    __syncthreads();
    if (tid < CH * K) {
        int k = tid % K, ch = tid / K;
        float s = 0.f;
#pragma unroll
        for (int r = 0; r < RW; ++r) s += sh[(ch * RW + r) * S + k];
        tmp[ch * K + k] = s;
    }
    __syncthreads();
    if (tid < K) {
        float s = 0.f;
#pragma unroll
        for (int ch = 0; ch < CH; ++ch) s += tmp[ch * K + tid];
        part_out[(size_t)bid * K + tid] = s;
    }
}

// ---- finalize BN stats: coalesced row-wise accumulation + padded-transpose reduce ----
template <int C>
__device__ void finalize_ss(const float* __restrict__ part, int nb, int n,
                            const float* __restrict__ g, const float* __restrict__ bb,
                            float* ss) {
    constexpr int K = 2 * C;
    constexpr int S = K + 1;
    constexpr int CH = 16;
    constexpr int RW = TB / CH;
    __shared__ float sh[TB * S];
    __shared__ float tmp[CH * K];
    __shared__ float tot[K];
    int tid = threadIdx.x;
    float v[K];
#pragma unroll
    for (int k = 0; k < K; ++k) v[k] = 0.f;
    for (int r = tid; r < nb; r += TB) {
        const float* row = part + (size_t)r * K;
        if constexpr (K == 16) {
            const float4* r4 = (const float4*)row;   // rows 64B-aligned
#pragma unroll
            for (int q = 0; q < 4; ++q) {
                float4 p = r4[q];
                v[q * 4 + 0] += p.x; v[q * 4 + 1] += p.y;
                v[q * 4 + 2] += p.z; v[q * 4 + 3] += p.w;
            }
        } else {
#pragma unroll
            for (int k = 0; k < K; ++k) v[k] += row[k];
        }
    }
#pragma unroll
    for (int k = 0; k < K; ++k) sh[tid * S + k] = v[k];
    __syncthreads();
    if (tid < CH * K) {
        int k = tid % K, ch = tid / K;
        float s = 0.f;
#pragma unroll
        for (int r = 0; r < RW; ++r) s += sh[(ch * RW + r) * S + k];
        tmp[ch * K + k] = s;
    }
    __syncthreads();
    if (tid < K) {
        float s = 0.f;
#pragma unroll
        for (int ch = 0; ch < CH; ++ch) s += tmp[ch * K + tid];
        tot[tid] = s;
    }
    __syncthreads();
    if (tid < C) {
        double mean = (double)tot[tid] / (double)n;
        double var = (double)tot[C + tid] / (double)n - mean * mean;
        if (var < 0.0) var = 0.0;
        float rstd = (float)(1.0 / sqrt(var + 1e-5));
        float sc = g[tid] * rstd;
        ss[tid] = sc;
        ss[C + tid] = bb[tid] - (float)mean * sc;
    }
    __syncthreads();
}

// ================= Kernel A: fc_age + fc -> fp32 (N1,3) + stats(3) =================
__global__ void k_fc_stats(const float* __restrict__ age,
                           const float* __restrict__ aw, const float* __restrict__ ab,
                           const float* __restrict__ w, const float* __restrict__ b,
                           float* __restrict__ out, float* __restrict__ part) {
    __shared__ float xs[64];
    int tid = threadIdx.x;
    if (tid < 64) xs[tid] = age[0] * aw[tid] + ab[tid];
    __syncthreads();
    int i = blockIdx.x * TB + tid;
    float val = 0.f;
    bool valid = i < 3 * N1;
    if (valid) {
        const float4* wr = (const float4*)(w + (size_t)i * 64);
        float acc = 0.f;
#pragma unroll
        for (int q = 0; q < 16; ++q) {
            float4 v = wr[q];
            acc = fmaf(v.x, xs[4 * q + 0], acc);
            acc = fmaf(v.y, xs[4 * q + 1], acc);
            acc = fmaf(v.z, xs[4 * q + 2], acc);
            acc = fmaf(v.w, xs[4 * q + 3], acc);
        }
        val = acc + b[i];
        out[i] = val;
    }
    float v[6] = {0, 0, 0, 0, 0, 0};
    if (valid) {
        float q = val * val;
        int c = i % 3;  // static-index accumulators (rule #20)
        if (c == 0)      { v[0] = val; v[3] = q; }
        else if (c == 1) { v[1] = val; v[4] = q; }
        else             { v[2] = val; v[5] = q; }
    }
    block_reduce_part<6>(v, part, blockIdx.x);
}

// ================= Kernel B: BN+LReLU + 3->21 linear + scatter -> fp16 rows + stats(3) ====
__device__ inline float yv(const float* a, const float* wsm, const float* bsm, int col) {
    return fmaf(a[0], wsm[col * 3 + 0],
           fmaf(a[1], wsm[col * 3 + 1],
           fmaf(a[2], wsm[col * 3 + 2], bsm[col])));
}

template <bool SRC16>
__global__ void k_up_fused(const void* __restrict__ xsrc, int R, int Nn,
                           const float* __restrict__ part, int nb, int nprev,
                           const float* __restrict__ g, const float* __restrict__ bb,
                           const float* __restrict__ w, const float* __restrict__ b,
                           const int* __restrict__ top, const int* __restrict__ down,
                           uint2* __restrict__ out, float* __restrict__ opart) {
    __shared__ float ss[6];
    __shared__ float wsm[63], bsm[21];
    finalize_ss<3>(part, nb, nprev, g, bb, ss);
    int tid = threadIdx.x;
    if (tid < 63) wsm[tid] = w[tid];
    if (tid < 21) bsm[tid] = b[tid];
    __syncthreads();
    float sc0 = ss[0], sc1 = ss[1], sc2 = ss[2];
    float sh0 = ss[3], sh1 = ss[4], sh2 = ss[5];
    int i = blockIdx.x * TB + tid;
    float o0 = 0.f, o1 = 0.f, o2 = 0.f;
    bool valid = i < Nn;
    if (valid) {
        auto loadact = [&](int r, float* a) {
            if constexpr (SRC16) {
                uint2 vv = ((const uint2*)xsrc)[r];
                float2 p = unpackh2(vv.x), q = unpackh2(vv.y);
                a[0] = p.x; a[1] = p.y; a[2] = q.x;
            } else {
                const float* xf = (const float*)xsrc;
                a[0] = xf[(size_t)r * 3 + 0];
                a[1] = xf[(size_t)r * 3 + 1];
                a[2] = xf[(size_t)r * 3 + 2];
            }
            float u0 = fmaf(a[0], sc0, sh0); a[0] = u0 >= 0.f ? u0 : SLOPE * u0;
            float u1 = fmaf(a[1], sc1, sh1); a[1] = u1 >= 0.f ? u1 : SLOPE * u1;
            float u2 = fmaf(a[2], sc2, sh2); a[2] = u2 >= 0.f ? u2 : SLOPE * u2;
        };
        if (i < R) {
            int t = top[i];
            int r = t / 7, jg = t % 7;
            float a[3];
            loadact(r, a);
            o0 = yv(a, wsm, bsm, jg * 3 + 0);
            o1 = yv(a, wsm, bsm, jg * 3 + 1);
            o2 = yv(a, wsm, bsm, jg * 3 + 2);
        } else {
            int k2 = i - R;
            int d0 = down[2 * k2 + 0];
            int d1 = down[2 * k2 + 1];
            int r0 = d0 / 7, j0 = d0 % 7;
            int r1 = d1 / 7, j1 = d1 % 7;
            float a0[3], a1[3];
            loadact(r0, a0);
            loadact(r1, a1);
            float y00 = yv(a0, wsm, bsm, j0 * 3 + 0);
            float y01 = yv(a0, wsm, bsm, j0 * 3 + 1);
            float y02 = yv(a0, wsm, bsm, j0 * 3 + 2);
            float y10 = yv(a1, wsm, bsm, j1 * 3 + 0);
            float y11 = yv(a1, wsm, bsm, j1 * 3 + 1);
            float y12 = yv(a1, wsm, bsm, j1 * 3 + 2);
            // y[down].reshape(-1,3,2).mean(-1): channel-mixing across the row pair
            o0 = 0.5f * (y00 + y01);
            o1 = 0.5f * (y02 + y10);
            o2 = 0.5f * (y11 + y12);
        }
        out[i] = make_uint2(packh2(o0, o1), packh2(o2, 0.f));
    }
    float v[6] = {0, 0, 0, 0, 0, 0};
    if (valid) {
        v[0] = o0; v[1] = o1; v[2] = o2;
        v[3] = o0 * o0; v[4] = o1 * o1; v[5] = o2 * o2;
    }
    block_reduce_part<6>(v, opart, blockIdx.x);
}

// ---- partial conv over neighbor range [J0, J0+NJ): gathers + SGPR-weight FMAs ----
template <int CIN, int COUT, int J0, int NJ>
__device__ inline void conv_partial(const void* __restrict__ xsrc,
                                    const int* __restrict__ np,
                                    const float* sc, const float* sh,
                                    const float* __restrict__ w, float* acc) {
    int vn[NJ];
#pragma unroll
    for (int k = 0; k < NJ; ++k) vn[k] = np[J0 + k];
    if constexpr (CIN == 3) {
        uint2 rows[NJ];
#pragma unroll
        for (int k = 0; k < NJ; ++k) rows[k] = ((const uint2*)xsrc)[vn[k]];
#pragma unroll
        for (int k = 0; k < NJ; ++k) {
            float2 p = unpackh2(rows[k].x), q = unpackh2(rows[k].y);
            float xv[3] = {p.x, p.y, q.x};
#pragma unroll
            for (int c = 0; c < 3; ++c) {
                float t = fmaf(xv[c], sc[c], sh[c]);
                t = t >= 0.f ? t : SLOPE * t;
#pragma unroll
                for (int o = 0; o < COUT; ++o)
                    acc[o] = fmaf(t, w[o * 21 + (J0 + k) * 3 + c], acc[o]);  // SGPR
            }
        }
    } else {
        uint4 rows[NJ];
#pragma unroll
        for (int k = 0; k < NJ; ++k) rows[k] = ((const uint4*)xsrc)[vn[k]];
#pragma unroll
        for (int k = 0; k < NJ; ++k) {
            float2 p0 = unpackh2(rows[k].x), p1 = unpackh2(rows[k].y);
            float2 p2 = unpackh2(rows[k].z), p3 = unpackh2(rows[k].w);
            float xv[8] = {p0.x, p0.y, p1.x, p1.y, p2.x, p2.y, p3.x, p3.y};
#pragma unroll
            for (int c = 0; c < 8; ++c) {
                float t = fmaf(xv[c], sc[c], sh[c]);
                t = t >= 0.f ? t : SLOPE * t;
#pragma unroll
                for (int o = 0; o < COUT; ++o)
                    acc[o] = fmaf(t, w[o * 56 + (J0 + k) * 8 + c], acc[o]);  // SGPR
            }
        }
    }
}

// ===== Kernel C: wave-pair J-SPLIT conv. Waves (2m,2m+1) cover the same 64 vertices;
// even wave gathers j=0..3, odd wave j=4..6 (NO duplicate gathers). j-range is
// wave-uniform -> weight indices stay SGPR. Combine once via padded LDS (stride 9/3,
// conflict-free). Grid 1281 blocks -> 2x waves for gather-latency hiding. =====
template <int CIN, int COUT, bool STATS, bool OUT16>
__global__ void k_conv_jsplit(const void* __restrict__ xsrc, const int* __restrict__ neigh,
                              const float* __restrict__ part, int nb,
                              const float* __restrict__ g, const float* __restrict__ bb,
                              const float* __restrict__ w, const float* __restrict__ b,
                              void* __restrict__ outv, float* __restrict__ opart) {
    constexpr int PS = (COUT == 8) ? 9 : 3;    // padded stride (odd -> conflict-free)
    __shared__ float ss[2 * CIN];
    __shared__ float comb[2][64][PS];
    finalize_ss<CIN>(part, nb, N3, g, bb, ss);
    int tid = threadIdx.x;

    float sc[CIN], sh[CIN];
#pragma unroll
    for (int c = 0; c < CIN; ++c) { sc[c] = ss[c]; sh[c] = ss[CIN + c]; }

    int wid = tid >> 6, lane = tid & 63;
    int pair = wid >> 1, sub = wid & 1;        // wave-uniform
    int vtx = blockIdx.x * 128 + pair * 64 + lane;
    bool valid = vtx < N3;

    float acc[COUT];
#pragma unroll
    for (int o = 0; o < COUT; ++o) acc[o] = (sub == 0) ? b[o] : 0.f;

    if (valid) {
        const int* np = neigh + (size_t)vtx * 7;
        if (sub == 0) conv_partial<CIN, COUT, 0, 4>(xsrc, np, sc, sh, w, acc);
        else          conv_partial<CIN, COUT, 4, 3>(xsrc, np, sc, sh, w, acc);
    }

    // odd wave deposits its partial acc; even wave combines and writes output
    if (valid && sub == 1) {
#pragma unroll
        for (int o = 0; o < COUT; ++o) comb[pair][lane][o] = acc[o];
    }
    __syncthreads();
    if (valid && sub == 0) {
#pragma unroll
        for (int o = 0; o < COUT; ++o) acc[o] += comb[pair][lane][o];
        if constexpr (OUT16) {
            uint4 ov;
            ov.x = packh2(acc[0], acc[1]); ov.y = packh2(acc[2], acc[3]);
            ov.z = packh2(acc[4], acc[5]); ov.w = packh2(acc[6], acc[7]);
            ((uint4*)outv)[vtx] = ov;
        } else {
            ((float2*)outv)[vtx] = make_float2(acc[0], acc[1]);
        }
    }

    if constexpr (STATS) {
        float v[2 * COUT];
#pragma unroll
        for (int o = 0; o < COUT; ++o) {
            float t = (valid && sub == 0) ? acc[o] : 0.f;   // count each vertex once
            v[o] = t;
            v[COUT + o] = t * t;
        }
        block_reduce_part<2 * COUT>(v, opart, blockIdx.x);
    }
}

extern "C" void kernel_launch(void* const* d_in, const int* in_sizes, int n_in,
                              void* d_out, int out_size, void* d_ws, size_t ws_size,
                              hipStream_t stream) {
    const float* age      = (const float*)d_in[0];
    const float* fc_age_w = (const float*)d_in[1];
    const float* fc_age_b = (const float*)d_in[2];
    const float* fc_w     = (const float*)d_in[3];
    const float* fc_b     = (const float*)d_in[4];
    const float* bn_up0_g = (const float*)d_in[5];
    const float* bn_up0_b = (const float*)d_in[6];
    const float* up0_w    = (const float*)d_in[7];
    const float* up0_b    = (const float*)d_in[8];
    const float* bn_up1_g = (const float*)d_in[9];
    const float* bn_up1_b = (const float*)d_in[10];
    const float* up1_w    = (const float*)d_in[11];
    const float* up1_b    = (const float*)d_in[12];
    const float* bn0_g    = (const float*)d_in[13];
    const float* bn0_b    = (const float*)d_in[14];
    const float* conv0_w  = (const float*)d_in[15];
    const float* conv0_b  = (const float*)d_in[16];
    const float* bn1_g    = (const float*)d_in[17];
    const float* bn1_b    = (const float*)d_in[18];
    const float* conv1_w  = (const float*)d_in[19];
    const float* conv1_b  = (const float*)d_in[20];
    const float* bn2_g    = (const float*)d_in[21];
    const float* bn2_b    = (const float*)d_in[22];
    const float* conv2_w  = (const float*)d_in[23];
    const float* conv2_b  = (const float*)d_in[24];
    const int* up_top0    = (const int*)d_in[25];
    const int* up_down0   = (const int*)d_in[26];
    const int* up_top1    = (const int*)d_in[27];
    const int* up_down1   = (const int*)d_in[28];
    const int* neigh      = (const int*)d_in[29];

    // workspace layout (byte offsets; partial-row bases 64B-aligned for float4 reads)
    char* base = (char*)d_ws;
    float* bufA = (float*)base;                        // (N1,3) fp32
    uint2* up0o = (uint2*)(base + 0x020000);           // (N2) 4h rows
    uint2* up1o = (uint2*)(base + 0x080000);           // (N3) 4h rows
    uint4* c0o  = (uint4*)(base + 0x200000);           // (N3) 8h rows
    uint4* c1o  = (uint4*)(base + 0x500000);           // (N3) 8h rows
    float* fbase = (float*)(base + 0x800000);
    float* partA  = fbase;                  // 121*6
    float* partB0 = partA + 1024;           // 161*6
    float* partB1 = partB0 + 1024;          // 641*6
    float* partC0 = partB1 + 4096;          // 1281*16 (offset 24576B, 64B ✓)
    float* partC1 = partC0 + 20992;         // 1281*16 (offset 108544B, 64B ✓)

    const int nbA  = cdiv(3 * N1, TB);   // 121
    const int nbB0 = cdiv(N2, TB);       // 161
    const int nbB1 = cdiv(N3, TB);       // 641
    const int nbJ  = cdiv(N3, 128);      // 1281 (j-split: 128 vertices/block)

    // 1) fc_age + fc -> bufA (N1,3) fp32, stats -> partA
    k_fc_stats<<<nbA, TB, 0, stream>>>(age, fc_age_w, fc_age_b, fc_w, fc_b, bufA, partA);

    // 2) up0: N1 -> N2 (fp32 -> fp16 rows), finalize partA, emit partB0
    k_up_fused<false><<<nbB0, TB, 0, stream>>>(bufA, N1, N2, partA, nbA, N1,
                                               bn_up0_g, bn_up0_b, up0_w, up0_b,
                                               up_top0, up_down0, up0o, partB0);

    // 3) up1: N2 -> N3 (fp16 -> fp16 rows), finalize partB0, emit partB1
    k_up_fused<true><<<nbB1, TB, 0, stream>>>(up0o, N2, N3, partB0, nbB0, N2,
                                              bn_up1_g, bn_up1_b, up1_w, up1_b,
                                              up_top1, up_down1, up1o, partB1);

    // 4) conv0: (N3,3)h -> (N3,8)h, finalize partB1 (nb=641), emit partC0 (nb=nbJ)
    k_conv_jsplit<3, 8, true, true><<<nbJ, TB, 0, stream>>>(up1o, neigh, partB1, nbB1,
                                                            bn0_g, bn0_b, conv0_w, conv0_b,
                                                            c0o, partC0);

    // 5) conv1: (N3,8)h -> (N3,8)h, finalize partC0 (nb=nbJ), emit partC1
    k_conv_jsplit<8, 8, true, true><<<nbJ, TB, 0, stream>>>(c0o, neigh, partC0, nbJ,
                                                            bn1_g, bn1_b, conv1_w, conv1_b,
                                                            c1o, partC1);

    // 6) conv2: (N3,8)h -> (N3,2) fp32 d_out, finalize partC1 (nb=nbJ)
    k_conv_jsplit<8, 2, false, false><<<nbJ, TB, 0, stream>>>(c1o, neigh, partC1, nbJ,
                                                              bn2_g, bn2_b, conv2_w, conv2_b,
                                                              (float*)d_out, nullptr);
}

// Round 18
// 55.386 us; speedup vs baseline: 6.5605x; 6.5605x over previous
//
#include <hip/hip_runtime.h>
#include <hip/hip_fp16.h>
#include <math.h>

#define N1 10242
#define N2 40962
#define N3 163842

constexpr float SLOPE = 0.2f;
constexpr int TB = 256;

static inline int cdiv(int a, int b) { return (a + b - 1) / b; }

typedef unsigned int u32;

__device__ inline u32 packh2(float a, float b) {
    __half2 h = __floats2half2_rn(a, b);
    return *reinterpret_cast<u32*>(&h);
}
__device__ inline float2 unpackh2(u32 v) {
    __half2 h;
    *reinterpret_cast<u32*>(&h) = v;
    return __half22float2(h);
}

// ---- block reduce of K fp32 per thread via padded LDS transpose (conflict-free) ----
template <int K>
__device__ void block_reduce_part(const float* v, float* __restrict__ part_out, int bid) {
    constexpr int S = K + 1;
    constexpr int CH = 16;            // chunks
    constexpr int RW = TB / CH;       // rows per chunk = 16
    __shared__ float sh[TB * S];
    __shared__ float tmp[CH * K];
    int tid = threadIdx.x;
#pragma unroll
    for (int k = 0; k < K; ++k) sh[tid * S + k] = v[k];
    __syncthreads();
    if (tid < CH * K) {
        int k = tid % K, ch = tid / K;
        float s = 0.f;
#pragma unroll
        for (int r = 0; r < RW; ++r) s += sh[(ch * RW + r) * S + k];
        tmp[ch * K + k] = s;
    }
    __syncthreads();
    if (tid < K) {
        float s = 0.f;
#pragma unroll
        for (int ch = 0; ch < CH; ++ch) s += tmp[ch * K + tid];
        part_out[(size_t)bid * K + tid] = s;
    }
}

// ---- finalize BN stats: COALESCED row-wise accumulation (each thread sums whole rows,
// every fetched line fully consumed) + padded-transpose LDS reduce -> scale/shift ----
template <int C>
__device__ void finalize_ss(const float* __restrict__ part, int nb, int n,
                            const float* __restrict__ g, const float* __restrict__ bb,
                            float* ss) {
    constexpr int K = 2 * C;
    constexpr int S = K + 1;
    constexpr int CH = 16;
    constexpr int RW = TB / CH;
    __shared__ float sh[TB * S];
    __shared__ float tmp[CH * K];
    __shared__ float tot[K];
    int tid = threadIdx.x;
    float v[K];
#pragma unroll
    for (int k = 0; k < K; ++k) v[k] = 0.f;
    // thread t accumulates rows t, t+TB, ... (<=3 rows at nb<=641), row-contiguous loads
    for (int r = tid; r < nb; r += TB) {
        const float* row = part + (size_t)r * K;
        if constexpr (K == 16) {
            const float4* r4 = (const float4*)row;   // rows are 64B-aligned
#pragma unroll
            for (int q = 0; q < 4; ++q) {
                float4 p = r4[q];
                v[q * 4 + 0] += p.x; v[q * 4 + 1] += p.y;
                v[q * 4 + 2] += p.z; v[q * 4 + 3] += p.w;
            }
        } else {
#pragma unroll
            for (int k = 0; k < K; ++k) v[k] += row[k];
        }
    }
    // padded-transpose reduce across the block -> tot[K]
#pragma unroll
    for (int k = 0; k < K; ++k) sh[tid * S + k] = v[k];
    __syncthreads();
    if (tid < CH * K) {
        int k = tid % K, ch = tid / K;
        float s = 0.f;
#pragma unroll
        for (int r = 0; r < RW; ++r) s += sh[(ch * RW + r) * S + k];
        tmp[ch * K + k] = s;
    }
    __syncthreads();
    if (tid < K) {
        float s = 0.f;
#pragma unroll
        for (int ch = 0; ch < CH; ++ch) s += tmp[ch * K + tid];
        tot[tid] = s;
    }
    __syncthreads();
    if (tid < C) {
        double mean = (double)tot[tid] / (double)n;
        double var = (double)tot[C + tid] / (double)n - mean * mean;
        if (var < 0.0) var = 0.0;
        float rstd = (float)(1.0 / sqrt(var + 1e-5));
        float sc = g[tid] * rstd;
        ss[tid] = sc;
        ss[C + tid] = bb[tid] - (float)mean * sc;
    }
    __syncthreads();
}

// ================= Kernel A: fc_age + fc -> fp32 (N1,3) + stats(3) =================
__global__ void k_fc_stats(const float* __restrict__ age,
                           const float* __restrict__ aw, const float* __restrict__ ab,
                           const float* __restrict__ w, const float* __restrict__ b,
                           float* __restrict__ out, float* __restrict__ part) {
    __shared__ float xs[64];
    int tid = threadIdx.x;
    if (tid < 64) xs[tid] = age[0] * aw[tid] + ab[tid];
    __syncthreads();
    int i = blockIdx.x * TB + tid;
    float val = 0.f;
    bool valid = i < 3 * N1;
    if (valid) {
        const float4* wr = (const float4*)(w + (size_t)i * 64);
        float acc = 0.f;
#pragma unroll
        for (int q = 0; q < 16; ++q) {
            float4 v = wr[q];
            acc = fmaf(v.x, xs[4 * q + 0], acc);
            acc = fmaf(v.y, xs[4 * q + 1], acc);
            acc = fmaf(v.z, xs[4 * q + 2], acc);
            acc = fmaf(v.w, xs[4 * q + 3], acc);
        }
        val = acc + b[i];
        out[i] = val;
    }
    float v[6] = {0, 0, 0, 0, 0, 0};
    if (valid) {
        float q = val * val;
        int c = i % 3;  // static-index accumulators (rule #20)
        if (c == 0)      { v[0] = val; v[3] = q; }
        else if (c == 1) { v[1] = val; v[4] = q; }
        else             { v[2] = val; v[5] = q; }
    }
    block_reduce_part<6>(v, part, blockIdx.x);
}

// ================= Kernel B: BN+LReLU + 3->21 linear + scatter -> fp16 rows + stats(3) ====
__device__ inline float yv(const float* a, const float* wsm, const float* bsm, int col) {
    return fmaf(a[0], wsm[col * 3 + 0],
           fmaf(a[1], wsm[col * 3 + 1],
           fmaf(a[2], wsm[col * 3 + 2], bsm[col])));
}

template <bool SRC16>
__global__ void k_up_fused(const void* __restrict__ xsrc, int R, int Nn,
                           const float* __restrict__ part, int nb, int nprev,
                           const float* __restrict__ g, const float* __restrict__ bb,
                           const float* __restrict__ w, const float* __restrict__ b,
                           const int* __restrict__ top, const int* __restrict__ down,
                           uint2* __restrict__ out, float* __restrict__ opart) {
    __shared__ float ss[6];
    __shared__ float wsm[63], bsm[21];
    finalize_ss<3>(part, nb, nprev, g, bb, ss);
    int tid = threadIdx.x;
    if (tid < 63) wsm[tid] = w[tid];
    if (tid < 21) bsm[tid] = b[tid];
    __syncthreads();
    float sc0 = ss[0], sc1 = ss[1], sc2 = ss[2];
    float sh0 = ss[3], sh1 = ss[4], sh2 = ss[5];
    int i = blockIdx.x * TB + tid;
    float o0 = 0.f, o1 = 0.f, o2 = 0.f;
    bool valid = i < Nn;
    if (valid) {
        auto loadact = [&](int r, float* a) {
            if constexpr (SRC16) {
                uint2 vv = ((const uint2*)xsrc)[r];
                float2 p = unpackh2(vv.x), q = unpackh2(vv.y);
                a[0] = p.x; a[1] = p.y; a[2] = q.x;
            } else {
                const float* xf = (const float*)xsrc;
                a[0] = xf[(size_t)r * 3 + 0];
                a[1] = xf[(size_t)r * 3 + 1];
                a[2] = xf[(size_t)r * 3 + 2];
            }
            float u0 = fmaf(a[0], sc0, sh0); a[0] = u0 >= 0.f ? u0 : SLOPE * u0;
            float u1 = fmaf(a[1], sc1, sh1); a[1] = u1 >= 0.f ? u1 : SLOPE * u1;
            float u2 = fmaf(a[2], sc2, sh2); a[2] = u2 >= 0.f ? u2 : SLOPE * u2;
        };
        if (i < R) {
            int t = top[i];
            int r = t / 7, jg = t % 7;
            float a[3];
            loadact(r, a);
            o0 = yv(a, wsm, bsm, jg * 3 + 0);
            o1 = yv(a, wsm, bsm, jg * 3 + 1);
            o2 = yv(a, wsm, bsm, jg * 3 + 2);
        } else {
            int k2 = i - R;
            int d0 = down[2 * k2 + 0];
            int d1 = down[2 * k2 + 1];
            int r0 = d0 / 7, j0 = d0 % 7;
            int r1 = d1 / 7, j1 = d1 % 7;
            float a0[3], a1[3];
            loadact(r0, a0);
            loadact(r1, a1);
            float y00 = yv(a0, wsm, bsm, j0 * 3 + 0);
            float y01 = yv(a0, wsm, bsm, j0 * 3 + 1);
            float y02 = yv(a0, wsm, bsm, j0 * 3 + 2);
            float y10 = yv(a1, wsm, bsm, j1 * 3 + 0);
            float y11 = yv(a1, wsm, bsm, j1 * 3 + 1);
            float y12 = yv(a1, wsm, bsm, j1 * 3 + 2);
            // y[down].reshape(-1,3,2).mean(-1): channel-mixing across the row pair
            o0 = 0.5f * (y00 + y01);
            o1 = 0.5f * (y02 + y10);
            o2 = 0.5f * (y11 + y12);
        }
        out[i] = make_uint2(packh2(o0, o1), packh2(o2, 0.f));
    }
    float v[6] = {0, 0, 0, 0, 0, 0};
    if (valid) {
        v[0] = o0; v[1] = o1; v[2] = o2;
        v[3] = o0 * o0; v[4] = o1 * o1; v[5] = o2 * o2;
    }
    block_reduce_part<6>(v, opart, blockIdx.x);
}

// ======= Kernel C: one-ring conv; weights via SCALAR path (uniform global, const idx) ====
template <int CIN, int COUT, bool STATS, bool OUT16>
__global__ void k_conv_sreg(const void* __restrict__ xsrc, const int* __restrict__ neigh,
                            const float* __restrict__ part, int nb,
                            const float* __restrict__ g, const float* __restrict__ bb,
                            const float* __restrict__ w, const float* __restrict__ b,
                            void* __restrict__ outv, float* __restrict__ opart) {
    __shared__ float ss[2 * CIN];
    finalize_ss<CIN>(part, nb, N3, g, bb, ss);
    int tid = threadIdx.x;

    float sc[CIN], sh[CIN];
#pragma unroll
    for (int c = 0; c < CIN; ++c) { sc[c] = ss[c]; sh[c] = ss[CIN + c]; }

    int i = blockIdx.x * TB + tid;
    bool valid = i < N3;

    float acc[COUT];
#pragma unroll
    for (int o = 0; o < COUT; ++o) acc[o] = b[o];   // uniform -> s_load

    if (valid) {
        const int* np = neigh + (size_t)i * 7;
        int vn[7];
#pragma unroll
        for (int j = 0; j < 7; ++j) vn[j] = np[j];

        if constexpr (CIN == 3) {
            uint2 rows[7];
#pragma unroll
            for (int j = 0; j < 7; ++j) rows[j] = ((const uint2*)xsrc)[vn[j]];
#pragma unroll
            for (int j = 0; j < 7; ++j) {
                float2 p = unpackh2(rows[j].x), q = unpackh2(rows[j].y);
                float xv[3] = {p.x, p.y, q.x};
#pragma unroll
                for (int c = 0; c < 3; ++c) {
                    float t = fmaf(xv[c], sc[c], sh[c]);
                    t = t >= 0.f ? t : SLOPE * t;
#pragma unroll
                    for (int o = 0; o < COUT; ++o)
                        acc[o] = fmaf(t, w[o * 21 + j * 3 + c], acc[o]);  // SGPR operand
                }
            }
        } else {
            uint4 rows[7];
#pragma unroll
            for (int j = 0; j < 7; ++j) rows[j] = ((const uint4*)xsrc)[vn[j]];
#pragma unroll
            for (int j = 0; j < 7; ++j) {
                float2 p0 = unpackh2(rows[j].x), p1 = unpackh2(rows[j].y);
                float2 p2 = unpackh2(rows[j].z), p3 = unpackh2(rows[j].w);
                float xv[8] = {p0.x, p0.y, p1.x, p1.y, p2.x, p2.y, p3.x, p3.y};
#pragma unroll
                for (int c = 0; c < 8; ++c) {
                    float t = fmaf(xv[c], sc[c], sh[c]);
                    t = t >= 0.f ? t : SLOPE * t;
#pragma unroll
                    for (int o = 0; o < COUT; ++o)
                        acc[o] = fmaf(t, w[o * 56 + j * 8 + c], acc[o]);  // SGPR operand
                }
            }
        }

        if constexpr (OUT16) {
            uint4 ov;
            ov.x = packh2(acc[0], acc[1]); ov.y = packh2(acc[2], acc[3]);
            ov.z = packh2(acc[4], acc[5]); ov.w = packh2(acc[6], acc[7]);
            ((uint4*)outv)[i] = ov;
        } else {
            ((float2*)outv)[i] = make_float2(acc[0], acc[1]);
        }
    }

    if constexpr (STATS) {
        float v[2 * COUT];
#pragma unroll
        for (int o = 0; o < COUT; ++o) {
            float t = valid ? acc[o] : 0.f;
            v[o] = t;
            v[COUT + o] = t * t;
        }
        block_reduce_part<2 * COUT>(v, opart, blockIdx.x);
    }
}

extern "C" void kernel_launch(void* const* d_in, const int* in_sizes, int n_in,
                              void* d_out, int out_size, void* d_ws, size_t ws_size,
                              hipStream_t stream) {
    const float* age      = (const float*)d_in[0];
    const float* fc_age_w = (const float*)d_in[1];
    const float* fc_age_b = (const float*)d_in[2];
    const float* fc_w     = (const float*)d_in[3];
    const float* fc_b     = (const float*)d_in[4];
    const float* bn_up0_g = (const float*)d_in[5];
    const float* bn_up0_b = (const float*)d_in[6];
    const float* up0_w    = (const float*)d_in[7];
    const float* up0_b    = (const float*)d_in[8];
    const float* bn_up1_g = (const float*)d_in[9];
    const float* bn_up1_b = (const float*)d_in[10];
    const float* up1_w    = (const float*)d_in[11];
    const float* up1_b    = (const float*)d_in[12];
    const float* bn0_g    = (const float*)d_in[13];
    const float* bn0_b    = (const float*)d_in[14];
    const float* conv0_w  = (const float*)d_in[15];
    const float* conv0_b  = (const float*)d_in[16];
    const float* bn1_g    = (const float*)d_in[17];
    const float* bn1_b    = (const float*)d_in[18];
    const float* conv1_w  = (const float*)d_in[19];
    const float* conv1_b  = (const float*)d_in[20];
    const float* bn2_g    = (const float*)d_in[21];
    const float* bn2_b    = (const float*)d_in[22];
    const float* conv2_w  = (const float*)d_in[23];
    const float* conv2_b  = (const float*)d_in[24];
    const int* up_top0    = (const int*)d_in[25];
    const int* up_down0   = (const int*)d_in[26];
    const int* up_top1    = (const int*)d_in[27];
    const int* up_down1   = (const int*)d_in[28];
    const int* neigh      = (const int*)d_in[29];

    // workspace layout (byte offsets, all 64B-aligned where rows are float4-read)
    char* base = (char*)d_ws;
    float* bufA = (float*)base;                        // (N1,3) fp32
    uint2* up0o = (uint2*)(base + 0x020000);           // (N2) 4h rows
    uint2* up1o = (uint2*)(base + 0x080000);           // (N3) 4h rows
    uint4* c0o  = (uint4*)(base + 0x200000);           // (N3) 8h rows
    uint4* c1o  = (uint4*)(base + 0x500000);           // (N3) 8h rows
    float* fbase = (float*)(base + 0x800000);
    float* partA  = fbase;                  // 121*6
    float* partB0 = partA + 1024;           // 161*6
    float* partB1 = partB0 + 1024;          // 641*6
    float* partC0 = partB1 + 4096;          // 641*16 (offset 24576B, 64B-aligned)
    float* partC1 = partC0 + 10752;         // 641*16 (offset 67584B, 64B-aligned)

    const int nbA  = cdiv(3 * N1, TB);  // 121
    const int nbB0 = cdiv(N2, TB);      // 161
    const int nbB1 = cdiv(N3, TB);      // 641
    const int nbC  = cdiv(N3, TB);      // 641

    // 1) fc_age + fc -> bufA (N1,3) fp32, stats -> partA
    k_fc_stats<<<nbA, TB, 0, stream>>>(age, fc_age_w, fc_age_b, fc_w, fc_b, bufA, partA);

    // 2) up0: N1 -> N2 (fp32 -> fp16 rows), finalize partA, emit partB0
    k_up_fused<false><<<nbB0, TB, 0, stream>>>(bufA, N1, N2, partA, nbA, N1,
                                               bn_up0_g, bn_up0_b, up0_w, up0_b,
                                               up_top0, up_down0, up0o, partB0);

    // 3) up1: N2 -> N3 (fp16 -> fp16 rows), finalize partB0, emit partB1
    k_up_fused<true><<<nbB1, TB, 0, stream>>>(up0o, N2, N3, partB0, nbB0, N2,
                                              bn_up1_g, bn_up1_b, up1_w, up1_b,
                                              up_top1, up_down1, up1o, partB1);

    // 4) conv0: (N3,3)h -> (N3,8)h, finalize partB1, emit partC0
    k_conv_sreg<3, 8, true, true><<<nbC, TB, 0, stream>>>(up1o, neigh, partB1, nbB1,
                                                          bn0_g, bn0_b, conv0_w, conv0_b,
                                                          c0o, partC0);

    // 5) conv1: (N3,8)h -> (N3,8)h, finalize partC0, emit partC1
    k_conv_sreg<8, 8, true, true><<<nbC, TB, 0, stream>>>(c0o, neigh, partC0, nbC,
                                                          bn1_g, bn1_b, conv1_w, conv1_b,
                                                          c1o, partC1);

    // 6) conv2: (N3,8)h -> (N3,2) fp32 d_out, finalize partC1
    k_conv_sreg<8, 2, false, false><<<nbC, TB, 0, stream>>>(c1o, neigh, partC1, nbC,
                                                            bn2_g, bn2_b, conv2_w, conv2_b,
                                                            (float*)d_out, nullptr);
}